// Round 9
// baseline (715.145 us; speedup 1.0000x reference)
//
#include <hip/hip_runtime.h>
#include <hip/hip_cooperative_groups.h>

namespace cg = cooperative_groups;

typedef unsigned short u16;
typedef __attribute__((ext_vector_type(8))) short bf16x8;
typedef __attribute__((ext_vector_type(4))) float f32x4;

__device__ __forceinline__ u16 f2bf(float f) {
    unsigned u = __float_as_uint(f);
    unsigned r = u + 0x7fffu + ((u >> 16) & 1u);
    return (u16)(r >> 16);
}
__device__ __forceinline__ float bf2f(u16 h) {
    return __uint_as_float(((unsigned)h) << 16);
}

__device__ __forceinline__ void gload_lds16(const u16* g, u16* l) {
    __builtin_amdgcn_global_load_lds(
        (__attribute__((address_space(1))) unsigned int*)(u16*)g,
        (__attribute__((address_space(3))) unsigned int*)l,
        16, 0, 0);
}

// ---------- conversion work item (grid-stride friendly) ----------
// b<6144: x fp32->bf16; b<7872: W transpose+convert; b==7872: zero rowsum.
__device__ __forceinline__ void cvt_block(int b, u16* smem,
                                          const float* __restrict__ x,
                                          const float* __restrict__ W,
                                          u16* __restrict__ xb,
                                          u16* __restrict__ wt,
                                          float* __restrict__ rsum) {
    const int tid = threadIdx.x;
    if (b < 6144) {
        int i = b * 256 + tid;
        float4 f = ((const float4*)x)[i];
        ushort4 u;
        u.x = f2bf(f.x); u.y = f2bf(f.y); u.z = f2bf(f.z); u.w = f2bf(f.w);
        ((ushort4*)xb)[i] = u;
    } else if (b < 7872) {
        float (*t)[33] = (float(*)[33])smem;
        const int bb = b - 6144;
        const int j = bb / 576;
        const int rem = bb - j * 576;
        const int d0 = (rem % 24) * 32, o0 = (rem / 24) * 32;
        const int tx = tid & 31, ty = tid >> 5;
        __syncthreads();
#pragma unroll
        for (int i = 0; i < 4; i++) {
            int d = d0 + ty + i * 8;
            t[ty + i * 8][tx] = W[((long)j * 768 + d) * 768 + o0 + tx];
        }
        __syncthreads();
#pragma unroll
        for (int i = 0; i < 4; i++) {
            int o = o0 + ty + i * 8;
            wt[((long)j * 768 + o) * 768 + d0 + tx] = f2bf(t[tx][ty + i * 8]);
        }
    } else {
        const float4 z4 = {0.f, 0.f, 0.f, 0.f};
#pragma unroll
        for (int jj = 0; jj < 8; jj++) ((float4*)rsum)[tid * 8 + jj] = z4;
    }
}

// ---------- one GEMM tile, R4 configuration ----------
// BM=64, BN=128, BK=64, 16x16x32 bf16 core, single-buffered 24KB smem.
// MODE 0: QKV. y<12 -> Q/K direct; y>=12 -> V transposed into Vt via LDS.
// MODE 1: P~ = exp(s*scale) bf16 + per-row atomic rowsum.
// MODE 2: out = acc / rsum[row] -> fp32.
template <int MODE>
__device__ __forceinline__ void gemm_tile(
    u16* smem, int bx, int by, int bz,
    const u16* __restrict__ A, const u16* __restrict__ Bt,
    u16* __restrict__ o16, float* __restrict__ o32,
    u16* __restrict__ vt, float* __restrict__ rsum,
    int K, long sA, long sB, long sO, int ldc, float scale) {
    u16* As = smem;
    u16* Bs = smem + 64 * 64;

    const int tid = threadIdx.x;
    const int lane = tid & 63;
    const int wave = tid >> 6;

    const u16* Ab = A + (long)bz * sA + (long)bx * 64 * K;
    const u16* Bb = Bt + (long)bz * sB + (long)by * 128 * K;

    const int rl = lane >> 3;
    const int pc = lane & 7;
    const int q = lane >> 4;
    const int rA = lane & 15;
    const int wm = (wave >> 1) * 32;
    const int wn = (wave & 1) * 64;

    __syncthreads();            // protect smem reuse across consecutive tiles

    f32x4 acc[2][4];
    const f32x4 zero = {0.f, 0.f, 0.f, 0.f};
#pragma unroll
    for (int i = 0; i < 2; i++)
#pragma unroll
        for (int j = 0; j < 4; j++) acc[i][j] = zero;

    for (int k0 = 0; k0 < K; k0 += 64) {
        // XOR swizzle: LDS row r position p holds global chunk p^(r&7)
#pragma unroll
        for (int t = 0; t < 2; ++t) {
            const int issue = wave + t * 4;      // wave-uniform
            const int row = issue * 8 + rl;
            const int gc = pc ^ (row & 7);
            gload_lds16(Ab + (long)row * K + k0 + gc * 8, &As[issue * 512]);
        }
#pragma unroll
        for (int t = 0; t < 4; ++t) {
            const int issue = wave + t * 4;
            const int row = issue * 8 + rl;
            const int gc = pc ^ (row & 7);
            gload_lds16(Bb + (long)row * K + k0 + gc * 8, &Bs[issue * 512]);
        }
        __syncthreads();
#pragma unroll
        for (int kk = 0; kk < 64; kk += 32) {
            const int gchunk = (kk >> 3) + q;
            bf16x8 af[2], bfr[4];
#pragma unroll
            for (int mi = 0; mi < 2; ++mi) {
                const int R = wm + mi * 16 + rA;
                af[mi] = *(const bf16x8*)&As[R * 64 + ((gchunk ^ (R & 7)) << 3)];
            }
#pragma unroll
            for (int ni = 0; ni < 4; ++ni) {
                const int R = wn + ni * 16 + rA;
                bfr[ni] = *(const bf16x8*)&Bs[R * 64 + ((gchunk ^ (R & 7)) << 3)];
            }
#pragma unroll
            for (int mi = 0; mi < 2; ++mi)
#pragma unroll
                for (int ni = 0; ni < 4; ++ni)
                    acc[mi][ni] = __builtin_amdgcn_mfma_f32_16x16x32_bf16(
                        af[mi], bfr[ni], acc[mi][ni], 0, 0, 0);
        }
        __syncthreads();
    }

    // epilogue: C/D layout col=lane&15, row=quad*4+reg
    const int rowb = bx * 64 + wm + q * 4;
    const int colb = by * 128 + wn + rA;

    if (MODE == 0 && by >= 12) {
        u16* T = smem;
#pragma unroll
        for (int mi = 0; mi < 2; ++mi)
#pragma unroll
            for (int ni = 0; ni < 4; ++ni) {
                const int lc = wn + ni * 16 + rA;
#pragma unroll
                for (int r = 0; r < 4; ++r) {
                    const int lr = wm + mi * 16 + q * 4 + r;
                    T[lc * 72 + lr] = f2bf(acc[mi][ni][r]);
                }
            }
        __syncthreads();
        const int b = bx >> 5;
        const int s0 = (bx & 31) * 64;
        const int o0 = (by - 12) * 128;
        const int ol = tid >> 1, h = (tid & 1) * 32;
        u16* dst = vt + ((long)b * 768 + o0 + ol) * 2048 + s0 + h;
        const u16* src = &T[ol * 72 + h];
#pragma unroll
        for (int j = 0; j < 4; ++j)
            *(uint4*)(dst + j * 8) = *(const uint4*)(src + j * 8);
        return;
    }

#pragma unroll
    for (int mi = 0; mi < 2; ++mi) {
        if (MODE == 0) {
            const int seg = by / 6;           // 0=Q, 1=K (tile-uniform)
            const int ocol = colb - seg * 768;
#pragma unroll
            for (int ni = 0; ni < 4; ++ni)
#pragma unroll
                for (int r = 0; r < 4; ++r)
                    o16[(long)seg * 6291456 + (long)(rowb + mi * 16 + r) * 768 +
                        ocol + ni * 16] = f2bf(acc[mi][ni][r]);
        } else if (MODE == 1) {
            u16* dst = o16 + (long)bz * sO;
            float rs[4] = {0.f, 0.f, 0.f, 0.f};
#pragma unroll
            for (int ni = 0; ni < 4; ++ni)
#pragma unroll
                for (int r = 0; r < 4; ++r) {
                    const float p = __expf(acc[mi][ni][r] * scale);
                    const u16 pb = f2bf(p);
                    dst[(long)(rowb + mi * 16 + r) * ldc + colb + ni * 16] = pb;
                    rs[r] += bf2f(pb);
                }
#pragma unroll
            for (int r = 0; r < 4; ++r) {
#pragma unroll
                for (int off = 1; off <= 8; off <<= 1) rs[r] += __shfl_xor(rs[r], off);
                if (rA == 0)
                    atomicAdd(&rsum[bz * 2048 + rowb + mi * 16 + r], rs[r]);
            }
        } else {
            float* dst = o32 + (long)bz * sO;
            const float4 rs4 = *(const float4*)&rsum[bz * 2048 + rowb + mi * 16];
            const float inv[4] = {1.f / rs4.x, 1.f / rs4.y, 1.f / rs4.z, 1.f / rs4.w};
#pragma unroll
            for (int ni = 0; ni < 4; ++ni)
#pragma unroll
                for (int r = 0; r < 4; ++r)
                    dst[(long)(rowb + mi * 16 + r) * ldc + colb + ni * 16] =
                        acc[mi][ni][r] * inv[r];
        }
    }
}

// ---------- single cooperative kernel: cvt -> QKV -> exp(QK^T) -> PV ----------
// grid 768 = 3 blocks/CU; __launch_bounds__(256,3) caps VGPR at ~170 so
// cooperative validation (all 768 co-resident) passes with margin.
__global__ __launch_bounds__(256, 3)
void attn_kernel(const float* __restrict__ x, const float* __restrict__ W,
                 u16* __restrict__ xb, u16* __restrict__ wt,
                 u16* __restrict__ Qb, u16* __restrict__ Kb,
                 u16* __restrict__ Vt, u16* __restrict__ Sb,
                 float* __restrict__ rsum, float* __restrict__ out) {
    __shared__ __align__(16) u16 smem[12288];   // 24 KB
    cg::grid_group grid = cg::this_grid();
    const int G = gridDim.x;

    for (int b = blockIdx.x; b < 7873; b += G)
        cvt_block(b, smem, x, W, xb, wt, rsum);
    __threadfence();
    grid.sync();

    for (int t = blockIdx.x; t < 2304; t += G)       // 3 rounds exact
        gemm_tile<0>(smem, t % 128, t / 128, 0, xb, wt, Qb, nullptr, Vt, nullptr,
                     768, 0L, 0L, 0L, 768, 1.0f);
    __threadfence();
    grid.sync();

    for (int t = blockIdx.x; t < 2048; t += G)
        gemm_tile<1>(smem, t & 31, (t >> 5) & 15, t >> 9, Qb, Kb, Sb, nullptr,
                     nullptr, rsum, 768, 2048L * 768, 2048L * 768, 2048L * 2048,
                     2048, 0.057735026918962574f);
    __threadfence();
    grid.sync();

    for (int t = blockIdx.x; t < 768; t += G)        // 1 round exact
        gemm_tile<2>(smem, t & 31, (t / 32) % 6, t / 192, Sb, Vt, nullptr, out,
                     nullptr, rsum, 2048, 2048L * 2048, 768L * 2048, 2048L * 768,
                     768, 1.0f);
}

// ---------- fallback standalone kernels (R4 path) ----------
__global__ __launch_bounds__(256) void cvt_in_kernel(const float* __restrict__ x,
                                                     const float* __restrict__ W,
                                                     u16* __restrict__ xb,
                                                     u16* __restrict__ wt,
                                                     float* __restrict__ rsum) {
    __shared__ __align__(16) u16 smem[2176];    // float[32][33] = 4224B fits? no ->
    // NOTE: cvt_block's W branch needs 4224 B; size accordingly.
    cvt_block(blockIdx.x, smem, x, W, xb, wt, rsum);
}

template <int MODE>
__global__ __launch_bounds__(256)
void gemm_kernel(const u16* __restrict__ A, const u16* __restrict__ Bt,
                 u16* __restrict__ o16, float* __restrict__ o32,
                 u16* __restrict__ vt, float* __restrict__ rsum,
                 int K, long sA, long sB, long sO, int ldc, float scale) {
    __shared__ __align__(16) u16 smem[12288];
    gemm_tile<MODE>(smem, blockIdx.x, blockIdx.y, blockIdx.z,
                    A, Bt, o16, o32, vt, rsum, K, sA, sB, sO, ldc, scale);
}

extern "C" void kernel_launch(void* const* d_in, const int* in_sizes, int n_in,
                              void* d_out, int out_size, void* d_ws, size_t ws_size,
                              hipStream_t stream) {
    const float* x = (const float*)d_in[0];     // [4,2048,768]
    const float* w = (const float*)d_in[1];     // [3,768,768]
    float* out = (float*)d_out;                 // [4,2048,768]

    const long NX = 6291456L;   // 4*2048*768
    const long NS = 16777216L;  // 4*2048*2048

    // ws layout: [Sb: NS][Qb: NX][Kb: NX][Vt: NX][rowsum: 8192 f32]
    // xb+wt overlay the Sb region (dead before phase C writes Sb)
    u16* Sb = (u16*)d_ws;
    u16* xb = Sb;                 // NX
    u16* wt = Sb + NX;            // 1769472  (< NS)
    u16* Qb = Sb + NS;
    u16* Kb = Qb + NX;
    u16* Vt = Kb + NX;
    float* rowsum = (float*)(Vt + NX);

    void* args[] = {(void*)&x, (void*)&w, (void*)&xb, (void*)&wt,
                    (void*)&Qb, (void*)&Kb, (void*)&Vt, (void*)&Sb,
                    (void*)&rowsum, (void*)&out};
    hipError_t err = hipLaunchCooperativeKernel((const void*)attn_kernel,
                                                dim3(768), dim3(256),
                                                args, 0, stream);
    if (err != hipSuccess) {
        (void)hipGetLastError();   // clear sticky error, use fallback path
        cvt_in_kernel<<<7873, 256, 0, stream>>>(x, w, xb, wt, rowsum);
        gemm_kernel<0><<<dim3(128, 18, 1), 256, 0, stream>>>(
            xb, wt, Qb, nullptr, Vt, nullptr, 768, 0L, 0L, 0L, 768, 1.0f);
        gemm_kernel<1><<<dim3(32, 16, 4), 256, 0, stream>>>(
            Qb, Kb, Sb, nullptr, nullptr, rowsum, 768, 2048L * 768, 2048L * 768,
            2048L * 2048, 2048, 0.057735026918962574f);
        gemm_kernel<2><<<dim3(32, 6, 4), 256, 0, stream>>>(
            Sb, Vt, nullptr, out, nullptr, rowsum, 2048, 2048L * 2048,
            768L * 2048, 2048L * 768, 768, 1.0f);
    }
}